// Round 14
// baseline (401.274 us; speedup 1.0000x reference)
//
#include <hip/hip_runtime.h>
#include <hip/hip_bf16.h>

#define DIMD 256
#define DIMC 64
#define RPT  16            // rows (tokens) per tile
#define RSTRIDE 260        // floats per ring row: 256 + 4 pad -> bank-balanced b128 reads
#define TILEF (RPT * RSTRIDE)   // 4160 floats per ring slot
#define RING 8             // ring depth (tiles)

typedef __attribute__((ext_vector_type(8))) __bf16 bf16x8;
typedef __attribute__((ext_vector_type(4))) float f32x4;

__global__ __launch_bounds__(512, 2) void tree_node_kernel(
    const float* __restrict__ x,
    const float* __restrict__ w_router,
    const float* __restrict__ b_router,
    const float* __restrict__ w_left,
    const float* __restrict__ b_left,
    const float* __restrict__ w_right,
    const float* __restrict__ b_right,
    float* __restrict__ out,
    int tpb)                       // tiles per block
{
    __shared__ float xring[RING * TILEF];   // 133,120 B fp32 tile ring
    __shared__ float wr_s[DIMD];            // router weights
    __shared__ int   ready[RING];           // producer->consumer: fill count per slot
    __shared__ int   done[RING];            // consumer->producer: 4 per consumed tile

    volatile int* const vready = ready;
    volatile int* const vdone  = done;

    const int tid  = threadIdx.x;
    const int lane = tid & 63;
    const int wave = tid >> 6;              // 0-3 consumers, 4-7 producers
    const int g    = lane >> 4;
    const int m    = lane & 15;

    if (tid < RING) { ready[tid] = 0; done[tid] = 0; }
    if (tid < DIMD) wr_s[tid] = w_router[tid];
    __syncthreads();   // the ONLY block-wide barrier (roles diverge after)

    const int nblk = gridDim.x;  // dense front: tile t = j*nblk + blockIdx.x

    if (wave >= 4) {
        // ======================= PRODUCER =======================
        // Streams tiles j = p, p+4, p+8, ... into ring slot j&7 via
        // global_load_lds (1 KB/instr, 16/tile). Keeps 16-32 KB in flight
        // per wave; flags tile j-4 after vmcnt(16) proves its data landed.
        const int p = wave - 4;
        int flag_j = -1;
        for (int j = p; j < tpb; j += 4) {
            const int slot = j & 7;
            if (j >= 8) {   // wait: all 4 consumers finished previous occupant
                while (vdone[slot] < 4 * (j >> 3)) __builtin_amdgcn_s_sleep(2);
            }
            asm volatile("" ::: "memory");
            const size_t row0 = ((size_t)j * nblk + blockIdx.x) * RPT;
            const float* gs = x + row0 * DIMD + lane * 4;
            float* ls = &xring[slot * TILEF];
#pragma unroll
            for (int r = 0; r < RPT; ++r) {
                __builtin_amdgcn_global_load_lds(
                    (const __attribute__((address_space(1))) void*)(gs + (size_t)r * DIMD),
                    (__attribute__((address_space(3))) void*)(ls + r * RSTRIDE),
                    16, 0, 0);
            }
            if (flag_j >= 0) {
                asm volatile("s_waitcnt vmcnt(16)" ::: "memory");  // tile flag_j landed
                if (lane == 0) vready[flag_j & 7] = (flag_j >> 3) + 1;
            }
            flag_j = j;
        }
        asm volatile("s_waitcnt vmcnt(0)" ::: "memory");
        if (flag_j >= 0 && lane == 0) vready[flag_j & 7] = (flag_j >> 3) + 1;
    } else {
        // ======================= CONSUMER =======================
        // Wave w owns output cols [16w,16w+16). Operand-swapped MFMA
        // (v11-verified): acc[r] = out[token m][col colbase+g*4+r].
        const int colbase = wave * 16;
        bf16x8 wL[8], wR[8];
#pragma unroll
        for (int s = 0; s < 8; ++s)
#pragma unroll
            for (int jj = 0; jj < 8; ++jj) {
                const int k = s * 32 + g * 8 + jj;
                wL[s][jj] = (__bf16)w_left[k * DIMC + colbase + m];
                wR[s][jj] = (__bf16)w_right[k * DIMC + colbase + m];
            }
        float biasL4[4], biasR4[4];
#pragma unroll
        for (int r = 0; r < 4; ++r) {
            biasL4[r] = b_left[colbase + g * 4 + r];
            biasR4[r] = b_right[colbase + g * 4 + r];
        }
        const float brout = b_router[0];

        for (int j = 0; j < tpb; ++j) {
            const int slot = j & 7;
            const int want = (j >> 3) + 1;
            while (vready[slot] < want) __builtin_amdgcn_s_sleep(2);
            asm volatile("" ::: "memory");

            // lane (g,m): fp32 slice of token-row m, k = s*32+g*8..+8 (8 steps)
            const float* base = &xring[slot * TILEF + m * RSTRIDE + g * 8];
            f32x4 xs[16];
#pragma unroll
            for (int s = 0; s < 8; ++s) {
                xs[2 * s]     = *(const f32x4*)(base + s * 32);
                xs[2 * s + 1] = *(const f32x4*)(base + s * 32 + 4);
            }
            asm volatile("s_waitcnt lgkmcnt(0)" ::: "memory");   // slice in regs
            __builtin_amdgcn_sched_barrier(0);                   // rule #18 fence
            if (lane == 0) atomicAdd(&done[slot], 1);            // slot reusable

            // fp64 router partial + bf16 fragments + 16 MFMA
            double racc = 0.0;
            f32x4 accL = {0.f,0.f,0.f,0.f}, accR = {0.f,0.f,0.f,0.f};
#pragma unroll
            for (int s = 0; s < 8; ++s) {
                const f32x4 wlo = *(const f32x4*)&wr_s[s * 32 + g * 8];      // broadcast
                const f32x4 whi = *(const f32x4*)&wr_s[s * 32 + g * 8 + 4];  // broadcast
                bf16x8 a;
#pragma unroll
                for (int jj = 0; jj < 4; ++jj) {
                    a[jj]     = (__bf16)xs[2 * s][jj];
                    a[jj + 4] = (__bf16)xs[2 * s + 1][jj];
                    racc += (double)xs[2 * s][jj]     * (double)wlo[jj]
                          + (double)xs[2 * s + 1][jj] * (double)whi[jj];
                }
                accL = __builtin_amdgcn_mfma_f32_16x16x32_bf16(wL[s], a, accL, 0, 0, 0);
                accR = __builtin_amdgcn_mfma_f32_16x16x32_bf16(wR[s], a, accR, 0, 0, 0);
            }
            racc += __shfl_xor(racc, 16);
            racc += __shfl_xor(racc, 32);
            const bool lsel = ((float)(racc + (double)brout) > 0.0f);

            const size_t row0 = ((size_t)j * nblk + blockIdx.x) * RPT;
            f32x4 ov;
#pragma unroll
            for (int r = 0; r < 4; ++r)
                ov[r] = lsel ? (accL[r] + biasL4[r]) : (accR[r] + biasR4[r]);
            *(f32x4*)(out + (row0 + m) * DIMC + colbase + g * 4) = ov;
        }
    }
}

extern "C" void kernel_launch(void* const* d_in, const int* in_sizes, int n_in,
                              void* d_out, int out_size, void* d_ws, size_t ws_size,
                              hipStream_t stream) {
    const float* x        = (const float*)d_in[0];
    const float* w_router = (const float*)d_in[1];
    const float* b_router = (const float*)d_in[2];
    const float* w_left   = (const float*)d_in[3];
    const float* b_left   = (const float*)d_in[4];
    const float* w_right  = (const float*)d_in[5];
    const float* b_right  = (const float*)d_in[6];
    float* out = (float*)d_out;

    const int n_tok = in_sizes[0] / DIMD;   // 1,048,576
    const int grid  = 256;                  // 1 block/CU (LDS ~134 KB)
    const int tpb   = n_tok / (grid * RPT); // 256 tiles per block

    tree_node_kernel<<<grid, 512, 0, stream>>>(
        x, w_router, b_router, w_left, b_left, w_right, b_right, out, tpb);
}